// Round 1
// baseline (684.859 us; speedup 1.0000x reference)
//
#include <hip/hip_runtime.h>

#define N_NODES 50000
#define N_EDGES 800000

// ---------------------------------------------------------------------------
// deg[i] += 1 for each edge with dst==i
__global__ void deg_kernel(const int* __restrict__ dst, float* __restrict__ deg, int nE) {
    int i = blockIdx.x * blockDim.x + threadIdx.x;
    if (i < nE) atomicAdd(&deg[dst[i]], 1.0f);
}

// dinv[i] = rsqrt(deg[i] + 1)   (in-place over deg)
__global__ void dinv_kernel(float* __restrict__ deg, int n) {
    int i = blockIdx.x * blockDim.x + threadIdx.x;
    if (i < n) deg[i] = rsqrtf(deg[i] + 1.0f);
}

// ---------------------------------------------------------------------------
// out[M,N] = A[M,K] @ W[K,N], W staged in LDS. One output element per thread.
template <int K, int N>
__global__ void gemm_kernel(const float* __restrict__ A, const float* __restrict__ W,
                            float* __restrict__ out, int M) {
    __shared__ float sW[K * N];
    for (int i = threadIdx.x; i < K * N; i += blockDim.x) sW[i] = W[i];
    __syncthreads();

    int idx = blockIdx.x * blockDim.x + threadIdx.x;
    if (idx >= M * N) return;
    int row = idx / N;
    int col = idx - row * N;
    const float* a = A + row * K;
    float sum = 0.0f;
#pragma unroll
    for (int k = 0; k < K; ++k) sum = fmaf(a[k], sW[k * N + col], sum);
    out[idx] = sum;
}

// ---------------------------------------------------------------------------
// agg[i,f] = h[i,f] * dinv[i]^2 + b[f]   (self-loop term + bias)
template <int N>
__global__ void init_kernel(const float* __restrict__ h, const float* __restrict__ dinv,
                            const float* __restrict__ b, float* __restrict__ agg, int M) {
    int idx = blockIdx.x * blockDim.x + threadIdx.x;
    if (idx >= M * N) return;
    int row = idx / N;
    int col = idx - row * N;
    float di = dinv[row];
    agg[idx] = h[idx] * di * di + b[col];
}

// ---------------------------------------------------------------------------
// For each edge e: agg[dst[e], :] += h[src[e], :] * dinv[src]*dinv[dst]
// 32 lanes per edge; lane covers features f = lane + 32*j (coalesced).
template <int N>  // N multiple of 32
__global__ void edge_kernel(const int* __restrict__ src, const int* __restrict__ dst,
                            const float* __restrict__ h, const float* __restrict__ dinv,
                            float* __restrict__ agg, int nE) {
    int gid = blockIdx.x * blockDim.x + threadIdx.x;
    int e = gid >> 5;
    int lane = gid & 31;
    if (e >= nE) return;
    int s = src[e];
    int d = dst[e];
    float c = dinv[s] * dinv[d];
    const float* hs = h + (long)s * N;
    float* ad = agg + (long)d * N;
#pragma unroll
    for (int j = 0; j < N / 32; ++j) {
        int f = lane + j * 32;
        atomicAdd(&ad[f], hs[f] * c);
    }
}

// ---------------------------------------------------------------------------
extern "C" void kernel_launch(void* const* d_in, const int* in_sizes, int n_in,
                              void* d_out, int out_size, void* d_ws, size_t ws_size,
                              hipStream_t stream) {
    const float* x  = (const float*)d_in[0];
    const int*   ei = (const int*)d_in[1];       // [2, 800000] -> src row, dst row
    const float* W1 = (const float*)d_in[2];
    const float* b1 = (const float*)d_in[3];
    const float* W2 = (const float*)d_in[4];
    const float* b2 = (const float*)d_in[5];
    float* out = (float*)d_out;

    const int* src = ei;
    const int* dst = ei + N_EDGES;

    // workspace layout
    char* ws = (char*)d_ws;
    float* dinv = (float*)ws;                                // 50000 f  (0.2 MB)
    float* h1   = (float*)(ws + 204800);                     // 50000*96 f (19.2 MB); h2 reuses this
    float* agg1 = (float*)(ws + 204800 + 19200000);          // 50000*96 f (19.2 MB)
    float* h2   = h1;

    // 1) degree + dinv
    hipMemsetAsync(dinv, 0, N_NODES * sizeof(float), stream);
    deg_kernel<<<(N_EDGES + 255) / 256, 256, 0, stream>>>(dst, dinv, N_EDGES);
    dinv_kernel<<<(N_NODES + 255) / 256, 256, 0, stream>>>(dinv, N_NODES);

    // 2) layer 1: h1 = x @ W1
    {
        int total = N_NODES * 96;
        gemm_kernel<96, 96><<<(total + 255) / 256, 256, 0, stream>>>(x, W1, h1, N_NODES);
        init_kernel<96><<<(total + 255) / 256, 256, 0, stream>>>(h1, dinv, b1, agg1, N_NODES);
        long tthreads = (long)N_EDGES * 32;
        edge_kernel<96><<<(int)((tthreads + 255) / 256), 256, 0, stream>>>(src, dst, h1, dinv, agg1, N_EDGES);
    }

    // 3) layer 2: h2 = agg1 @ W2, aggregate straight into d_out
    {
        int total = N_NODES * 64;
        gemm_kernel<96, 64><<<(total + 255) / 256, 256, 0, stream>>>(agg1, W2, h2, N_NODES);
        init_kernel<64><<<(total + 255) / 256, 256, 0, stream>>>(h2, dinv, b2, out, N_NODES);
        long tthreads = (long)N_EDGES * 32;
        edge_kernel<64><<<(int)((tthreads + 255) / 256), 256, 0, stream>>>(src, dst, h2, dinv, out, N_EDGES);
    }
}

// Round 2
// 281.778 us; speedup vs baseline: 2.4305x; 2.4305x over previous
//
#include <hip/hip_runtime.h>

#define N_NODES 50000
#define N_EDGES 800000
#define NB_SCAN ((N_NODES + 255) / 256)   // 196 blocks for the hierarchical scan

// ---------------------------------------------------------------------------
// deg[i] += 1 for each edge with dst==i  (int histogram)
__global__ void deg_kernel(const int* __restrict__ dst, int* __restrict__ deg, int nE) {
    int i = blockIdx.x * blockDim.x + threadIdx.x;
    if (i < nE) atomicAdd(&deg[dst[i]], 1);
}

// dinv[i] = rsqrt(deg[i] + 1)
__global__ void dinv_kernel(const int* __restrict__ deg, float* __restrict__ dinv, int n) {
    int i = blockIdx.x * blockDim.x + threadIdx.x;
    if (i < n) dinv[i] = rsqrtf((float)deg[i] + 1.0f);
}

// ---------------------------------------------------------------------------
// Hierarchical exclusive scan of deg -> rowstart (3 kernels)
__global__ void scan1_kernel(const int* __restrict__ deg, int* __restrict__ rowstart,
                             int* __restrict__ bsum, int n) {
    __shared__ int s[256];
    int i = blockIdx.x * 256 + threadIdx.x;
    int v = (i < n) ? deg[i] : 0;
    s[threadIdx.x] = v;
    __syncthreads();
    for (int d = 1; d < 256; d <<= 1) {
        int t = (threadIdx.x >= d) ? s[threadIdx.x - d] : 0;
        __syncthreads();
        s[threadIdx.x] += t;
        __syncthreads();
    }
    if (i < n) rowstart[i] = s[threadIdx.x] - v;   // block-local exclusive
    if (threadIdx.x == 255) bsum[blockIdx.x] = s[255];
}

__global__ void scan2_kernel(int* __restrict__ bsum, int* __restrict__ boff, int nb) {
    __shared__ int s[256];
    int t = threadIdx.x;
    int v = (t < nb) ? bsum[t] : 0;
    s[t] = v;
    __syncthreads();
    for (int d = 1; d < 256; d <<= 1) {
        int x = (t >= d) ? s[t - d] : 0;
        __syncthreads();
        s[t] += x;
        __syncthreads();
    }
    if (t < nb) boff[t] = s[t] - v;                 // exclusive block offsets
    if (t == nb - 1) boff[nb] = s[t];               // grand total
}

__global__ void scan3_kernel(int* __restrict__ rowstart, int* __restrict__ cursor,
                             const int* __restrict__ boff, int n, int nb) {
    int i = blockIdx.x * 256 + threadIdx.x;
    if (i < n) {
        int v = rowstart[i] + boff[blockIdx.x];
        rowstart[i] = v;
        cursor[i] = v;
    }
    if (i == n - 1) rowstart[n] = boff[nb];
}

// ---------------------------------------------------------------------------
// CSR scatter: esrc/edinv sorted by dst
__global__ void scatter_kernel(const int* __restrict__ src, const int* __restrict__ dst,
                               const float* __restrict__ dinv, int* __restrict__ cursor,
                               int* __restrict__ esrc, float* __restrict__ edinv, int nE) {
    int i = blockIdx.x * blockDim.x + threadIdx.x;
    if (i >= nE) return;
    int s = src[i];
    int d = dst[i];
    int p = atomicAdd(&cursor[d], 1);
    esrc[p] = s;
    edinv[p] = dinv[s];
}

// ---------------------------------------------------------------------------
// W12 = W1 @ W2 (96x96 @ 96x64), bw = b1 @ W2
__global__ void wfuse_kernel(const float* __restrict__ W1, const float* __restrict__ W2,
                             const float* __restrict__ b1, float* __restrict__ W12,
                             float* __restrict__ bw) {
    int idx = blockIdx.x * blockDim.x + threadIdx.x;
    if (idx < 96 * 64) {
        int k = idx >> 6, nn = idx & 63;
        float s = 0.0f;
#pragma unroll
        for (int j = 0; j < 96; ++j) s = fmaf(W1[k * 96 + j], W2[j * 64 + nn], s);
        W12[idx] = s;
    } else if (idx < 96 * 64 + 64) {
        int nn = idx - 96 * 64;
        float s = 0.0f;
#pragma unroll
        for (int j = 0; j < 96; ++j) s = fmaf(b1[j], W2[j * 64 + nn], s);
        bw[nn] = s;
    }
}

// ---------------------------------------------------------------------------
// y[M,64] = x[M,96] @ W12[96,64], W12 staged in LDS; one output/thread.
__global__ void gemm_kernel(const float* __restrict__ A, const float* __restrict__ W,
                            float* __restrict__ out, int M) {
    __shared__ float sW[96 * 64];
    for (int i = threadIdx.x; i < 96 * 64; i += blockDim.x) sW[i] = W[i];
    __syncthreads();
    int idx = blockIdx.x * blockDim.x + threadIdx.x;
    if (idx >= M * 64) return;
    int row = idx >> 6;
    int col = idx & 63;
    const float* a = A + row * 96;
    float sum = 0.0f;
#pragma unroll
    for (int k = 0; k < 96; ++k) sum = fmaf(a[k], sW[k * 64 + col], sum);
    out[idx] = sum;
}

// ---------------------------------------------------------------------------
// One 64-lane wave per node: out[i,:] = dinv_i^2*y[i,:] + sum_e dinv_s*dinv_i*y[s,:]
// FINAL adds the rank-1 bias correction s_i*bw + b2.
template <bool FINAL>
__global__ void agg_kernel(const float* __restrict__ y, const int* __restrict__ rowstart,
                           const int* __restrict__ esrc, const float* __restrict__ edinv,
                           const float* __restrict__ dinv, const float* __restrict__ bw,
                           const float* __restrict__ b2, float* __restrict__ out, int n) {
    int wid = (blockIdx.x * blockDim.x + threadIdx.x) >> 6;
    int lane = threadIdx.x & 63;
    if (wid >= n) return;
    int rs = rowstart[wid];
    int re = rowstart[wid + 1];
    float di = dinv[wid];
    float acc = y[(long)wid * 64 + lane] * di * di;
    float sd = 0.0f;
    for (int base = rs; base < re; base += 64) {
        int idx = base + lane;
        bool ok = idx < re;
        int sj = ok ? esrc[idx] : 0;
        float dj = ok ? edinv[idx] : 0.0f;
        sd += dj;
        int nn = min(64, re - base);
        for (int j = 0; j < nn; ++j) {
            int s = __shfl(sj, j);
            float c = __shfl(dj, j) * di;
            acc = fmaf(y[(long)s * 64 + lane], c, acc);
        }
    }
    if (FINAL) {
#pragma unroll
        for (int m = 1; m < 64; m <<= 1) sd += __shfl_xor(sd, m);
        float si = di * (di + sd);
        acc = fmaf(si, bw[lane], acc) + b2[lane];
    }
    out[(long)wid * 64 + lane] = acc;
}

// ---------------------------------------------------------------------------
extern "C" void kernel_launch(void* const* d_in, const int* in_sizes, int n_in,
                              void* d_out, int out_size, void* d_ws, size_t ws_size,
                              hipStream_t stream) {
    const float* x  = (const float*)d_in[0];
    const int*   ei = (const int*)d_in[1];
    const float* W1 = (const float*)d_in[2];
    const float* b1 = (const float*)d_in[3];
    const float* W2 = (const float*)d_in[4];
    const float* b2 = (const float*)d_in[5];
    float* out = (float*)d_out;

    const int* src = ei;
    const int* dst = ei + N_EDGES;

    // workspace layout (bytes)
    char* ws = (char*)d_ws;
    float* dinv     = (float*)(ws + 0);                  // 204800
    int*   deg      = (int*)  (ws + 204800);             // 204800
    int*   rowstart = (int*)  (ws + 409600);             // 204800 (n+1 ints)
    int*   cursor   = (int*)  (ws + 614400);             // 204800
    int*   boff     = (int*)  (ws + 819200);             // 1024   (nb+1 ints)
    int*   bsum     = (int*)  (ws + 820224);             // 1024
    float* W12      = (float*)(ws + 821248);             // 24576
    float* bw       = (float*)(ws + 845824);             // 512
    int*   esrc     = (int*)  (ws + 846336);             // 3200000
    float* edinv    = (float*)(ws + 4046336);            // 3200000
    float* y        = (float*)(ws + 7246336);            // 12800000
    float* z        = (float*)(ws + 20046336);           // 12800000  (end ~32.8MB)

    // 1) degree + dinv
    hipMemsetAsync(deg, 0, N_NODES * sizeof(int), stream);
    deg_kernel<<<(N_EDGES + 255) / 256, 256, 0, stream>>>(dst, deg, N_EDGES);
    dinv_kernel<<<(N_NODES + 255) / 256, 256, 0, stream>>>(deg, dinv, N_NODES);

    // 2) CSR build
    scan1_kernel<<<NB_SCAN, 256, 0, stream>>>(deg, rowstart, bsum, N_NODES);
    scan2_kernel<<<1, 256, 0, stream>>>(bsum, boff, NB_SCAN);
    scan3_kernel<<<NB_SCAN, 256, 0, stream>>>(rowstart, cursor, boff, N_NODES, NB_SCAN);
    scatter_kernel<<<(N_EDGES + 255) / 256, 256, 0, stream>>>(src, dst, dinv, cursor,
                                                              esrc, edinv, N_EDGES);

    // 3) fused weights + single GEMM
    wfuse_kernel<<<(96 * 64 + 64 + 255) / 256, 256, 0, stream>>>(W1, W2, b1, W12, bw);
    gemm_kernel<<<(N_NODES * 64 + 255) / 256, 256, 0, stream>>>(x, W12, y, N_NODES);

    // 4) two aggregation passes: z = N y ; out = N z + s*bw + b2
    int aggBlocks = (N_NODES * 64 + 255) / 256;  // one 64-lane wave per node
    agg_kernel<false><<<aggBlocks, 256, 0, stream>>>(y, rowstart, esrc, edinv, dinv,
                                                     bw, b2, z, N_NODES);
    agg_kernel<true><<<aggBlocks, 256, 0, stream>>>(z, rowstart, esrc, edinv, dinv,
                                                    bw, b2, out, N_NODES);
}

// Round 3
// 239.764 us; speedup vs baseline: 2.8564x; 1.1752x over previous
//
#include <hip/hip_runtime.h>

#define N_NODES 50000
#define N_EDGES 800000
#define NB_SCAN ((N_NODES + 255) / 256)   // 196 blocks for the hierarchical scan

// ---------------------------------------------------------------------------
// deg[i] += 1 for each edge with dst==i  (int histogram)
__global__ void deg_kernel(const int* __restrict__ dst, int* __restrict__ deg, int nE) {
    int i = blockIdx.x * blockDim.x + threadIdx.x;
    if (i < nE) atomicAdd(&deg[dst[i]], 1);
}

// dinv[i] = rsqrt(deg[i] + 1)
__global__ void dinv_kernel(const int* __restrict__ deg, float* __restrict__ dinv, int n) {
    int i = blockIdx.x * blockDim.x + threadIdx.x;
    if (i < n) dinv[i] = rsqrtf((float)deg[i] + 1.0f);
}

// ---------------------------------------------------------------------------
// Hierarchical exclusive scan of deg -> rowstart (3 kernels)
__global__ void scan1_kernel(const int* __restrict__ deg, int* __restrict__ rowstart,
                             int* __restrict__ bsum, int n) {
    __shared__ int s[256];
    int i = blockIdx.x * 256 + threadIdx.x;
    int v = (i < n) ? deg[i] : 0;
    s[threadIdx.x] = v;
    __syncthreads();
    for (int d = 1; d < 256; d <<= 1) {
        int t = (threadIdx.x >= d) ? s[threadIdx.x - d] : 0;
        __syncthreads();
        s[threadIdx.x] += t;
        __syncthreads();
    }
    if (i < n) rowstart[i] = s[threadIdx.x] - v;   // block-local exclusive
    if (threadIdx.x == 255) bsum[blockIdx.x] = s[255];
}

__global__ void scan2_kernel(int* __restrict__ bsum, int* __restrict__ boff, int nb) {
    __shared__ int s[256];
    int t = threadIdx.x;
    int v = (t < nb) ? bsum[t] : 0;
    s[t] = v;
    __syncthreads();
    for (int d = 1; d < 256; d <<= 1) {
        int x = (t >= d) ? s[t - d] : 0;
        __syncthreads();
        s[t] += x;
        __syncthreads();
    }
    if (t < nb) boff[t] = s[t] - v;                 // exclusive block offsets
    if (t == nb - 1) boff[nb] = s[t];               // grand total
}

__global__ void scan3_kernel(int* __restrict__ rowstart, int* __restrict__ cursor,
                             const int* __restrict__ boff, int n, int nb) {
    int i = blockIdx.x * 256 + threadIdx.x;
    if (i < n) {
        int v = rowstart[i] + boff[blockIdx.x];
        rowstart[i] = v;
        cursor[i] = v;
    }
    if (i == n - 1) rowstart[n] = boff[nb];
}

// ---------------------------------------------------------------------------
// CSR scatter: esrc/edinv sorted by dst
__global__ void scatter_kernel(const int* __restrict__ src, const int* __restrict__ dst,
                               const float* __restrict__ dinv, int* __restrict__ cursor,
                               int* __restrict__ esrc, float* __restrict__ edinv, int nE) {
    int i = blockIdx.x * blockDim.x + threadIdx.x;
    if (i >= nE) return;
    int s = src[i];
    int d = dst[i];
    int p = atomicAdd(&cursor[d], 1);
    esrc[p] = s;
    edinv[p] = dinv[s];
}

// ---------------------------------------------------------------------------
// W12 = W1 @ W2 (96x96 @ 96x64), bw = b1 @ W2
__global__ void wfuse_kernel(const float* __restrict__ W1, const float* __restrict__ W2,
                             const float* __restrict__ b1, float* __restrict__ W12,
                             float* __restrict__ bw) {
    int idx = blockIdx.x * blockDim.x + threadIdx.x;
    if (idx < 96 * 64) {
        int k = idx >> 6, nn = idx & 63;
        float s = 0.0f;
#pragma unroll
        for (int j = 0; j < 96; ++j) s = fmaf(W1[k * 96 + j], W2[j * 64 + nn], s);
        W12[idx] = s;
    } else if (idx < 96 * 64 + 64) {
        int nn = idx - 96 * 64;
        float s = 0.0f;
#pragma unroll
        for (int j = 0; j < 96; ++j) s = fmaf(b1[j], W2[j * 64 + nn], s);
        bw[nn] = s;
    }
}

// ---------------------------------------------------------------------------
// y[M,64] = A[M,96] @ W[96,64]. 32 rows/block, 8 rows per thread (8 indep
// FMA chains), A-row base made wave-uniform -> scalar loads, float4 over k.
__global__ void gemm_kernel(const float* __restrict__ A, const float* __restrict__ W,
                            float* __restrict__ out, int M) {
    __shared__ float sW[96 * 64];
    {
        float4* sW4 = (float4*)sW;
        const float4* W4 = (const float4*)W;
        for (int i = threadIdx.x; i < 96 * 16; i += blockDim.x) sW4[i] = W4[i];
    }
    __syncthreads();

    int col = threadIdx.x & 63;
    int wav = threadIdx.x >> 6;                       // 0..3
    int row0 = __builtin_amdgcn_readfirstlane(blockIdx.x * 32 + wav * 8);
    if (row0 >= M) return;
    const float* a0 = A + (long)row0 * 96;
    float acc[8] = {0, 0, 0, 0, 0, 0, 0, 0};

    if (row0 + 8 <= M) {
#pragma unroll 4
        for (int k = 0; k < 96; k += 4) {
            float w0 = sW[(k + 0) * 64 + col];
            float w1 = sW[(k + 1) * 64 + col];
            float w2 = sW[(k + 2) * 64 + col];
            float w3 = sW[(k + 3) * 64 + col];
#pragma unroll
            for (int r = 0; r < 8; ++r) {
                float4 a = *(const float4*)(a0 + r * 96 + k);
                acc[r] = fmaf(a.x, w0, acc[r]);
                acc[r] = fmaf(a.y, w1, acc[r]);
                acc[r] = fmaf(a.z, w2, acc[r]);
                acc[r] = fmaf(a.w, w3, acc[r]);
            }
        }
#pragma unroll
        for (int r = 0; r < 8; ++r) out[(long)(row0 + r) * 64 + col] = acc[r];
    } else {
        int nr = M - row0;
        for (int k = 0; k < 96; k += 4) {
            float w0 = sW[(k + 0) * 64 + col];
            float w1 = sW[(k + 1) * 64 + col];
            float w2 = sW[(k + 2) * 64 + col];
            float w3 = sW[(k + 3) * 64 + col];
            for (int r = 0; r < nr; ++r) {
                float4 a = *(const float4*)(a0 + r * 96 + k);
                acc[r] = fmaf(a.x, w0, acc[r]);
                acc[r] = fmaf(a.y, w1, acc[r]);
                acc[r] = fmaf(a.z, w2, acc[r]);
                acc[r] = fmaf(a.w, w3, acc[r]);
            }
        }
        for (int r = 0; r < nr; ++r) out[(long)(row0 + r) * 64 + col] = acc[r];
    }
}

// ---------------------------------------------------------------------------
// One 64-lane wave per node: out[i,:] = dinv_i^2*y[i,:] + sum_e dinv_s*dinv_i*y[s,:]
// FINAL adds the rank-1 bias correction s_i*bw + b2.
template <bool FINAL>
__global__ void agg_kernel(const float* __restrict__ y, const int* __restrict__ rowstart,
                           const int* __restrict__ esrc, const float* __restrict__ edinv,
                           const float* __restrict__ dinv, const float* __restrict__ bw,
                           const float* __restrict__ b2, float* __restrict__ out, int n) {
    int wid = (blockIdx.x * blockDim.x + threadIdx.x) >> 6;
    int lane = threadIdx.x & 63;
    if (wid >= n) return;
    int rs = rowstart[wid];
    int re = rowstart[wid + 1];
    float di = dinv[wid];
    float acc = y[(long)wid * 64 + lane] * di * di;
    float sd = 0.0f;
    for (int base = rs; base < re; base += 64) {
        int idx = base + lane;
        bool ok = idx < re;
        int sj = ok ? esrc[idx] : 0;
        float dj = ok ? edinv[idx] : 0.0f;
        sd += dj;
        int nn = min(64, re - base);
        for (int j = 0; j < nn; ++j) {
            int s = __shfl(sj, j);
            float c = __shfl(dj, j) * di;
            acc = fmaf(y[(long)s * 64 + lane], c, acc);
        }
    }
    if (FINAL) {
#pragma unroll
        for (int m = 1; m < 64; m <<= 1) sd += __shfl_xor(sd, m);
        float si = di * (di + sd);
        acc = fmaf(si, bw[lane], acc) + b2[lane];
    }
    out[(long)wid * 64 + lane] = acc;
}

// ---------------------------------------------------------------------------
extern "C" void kernel_launch(void* const* d_in, const int* in_sizes, int n_in,
                              void* d_out, int out_size, void* d_ws, size_t ws_size,
                              hipStream_t stream) {
    const float* x  = (const float*)d_in[0];
    const int*   ei = (const int*)d_in[1];
    const float* W1 = (const float*)d_in[2];
    const float* b1 = (const float*)d_in[3];
    const float* W2 = (const float*)d_in[4];
    const float* b2 = (const float*)d_in[5];
    float* out = (float*)d_out;

    const int* src = ei;
    const int* dst = ei + N_EDGES;

    // workspace layout (bytes)
    char* ws = (char*)d_ws;
    float* dinv     = (float*)(ws + 0);                  // 204800
    int*   deg      = (int*)  (ws + 204800);             // 204800
    int*   rowstart = (int*)  (ws + 409600);             // 204800 (n+1 ints)
    int*   cursor   = (int*)  (ws + 614400);             // 204800
    int*   boff     = (int*)  (ws + 819200);             // 1024   (nb+1 ints)
    int*   bsum     = (int*)  (ws + 820224);             // 1024
    float* W12      = (float*)(ws + 821248);             // 24576
    float* bw       = (float*)(ws + 845824);             // 512
    int*   esrc     = (int*)  (ws + 846336);             // 3200000
    float* edinv    = (float*)(ws + 4046336);            // 3200000
    float* y        = (float*)(ws + 7246336);            // 12800000
    float* z        = (float*)(ws + 20046336);           // 12800000  (end ~32.8MB)

    // 1) degree + dinv
    hipMemsetAsync(deg, 0, N_NODES * sizeof(int), stream);
    deg_kernel<<<(N_EDGES + 255) / 256, 256, 0, stream>>>(dst, deg, N_EDGES);
    dinv_kernel<<<(N_NODES + 255) / 256, 256, 0, stream>>>(deg, dinv, N_NODES);

    // 2) CSR build
    scan1_kernel<<<NB_SCAN, 256, 0, stream>>>(deg, rowstart, bsum, N_NODES);
    scan2_kernel<<<1, 256, 0, stream>>>(bsum, boff, NB_SCAN);
    scan3_kernel<<<NB_SCAN, 256, 0, stream>>>(rowstart, cursor, boff, N_NODES, NB_SCAN);
    scatter_kernel<<<(N_EDGES + 255) / 256, 256, 0, stream>>>(src, dst, dinv, cursor,
                                                              esrc, edinv, N_EDGES);

    // 3) fused weights + single GEMM
    wfuse_kernel<<<(96 * 64 + 64 + 255) / 256, 256, 0, stream>>>(W1, W2, b1, W12, bw);
    gemm_kernel<<<(N_NODES + 31) / 32, 256, 0, stream>>>(x, W12, y, N_NODES);

    // 4) two aggregation passes: z = N y ; out = N z + s*bw + b2
    int aggBlocks = (N_NODES * 64 + 255) / 256;  // one 64-lane wave per node
    agg_kernel<false><<<aggBlocks, 256, 0, stream>>>(y, rowstart, esrc, edinv, dinv,
                                                     bw, b2, z, N_NODES);
    agg_kernel<true><<<aggBlocks, 256, 0, stream>>>(z, rowstart, esrc, edinv, dinv,
                                                    bw, b2, out, N_NODES);
}

// Round 4
// 201.577 us; speedup vs baseline: 3.3975x; 1.1894x over previous
//
#include <hip/hip_runtime.h>

#define N_NODES 50000
#define N_EDGES 800000
#define NB_SCAN ((N_NODES + 255) / 256)   // 196 blocks for the hierarchical scan

// ---------------------------------------------------------------------------
// deg[i] += 1 for each edge with dst==i  (int histogram)
__global__ void deg_kernel(const int* __restrict__ dst, int* __restrict__ deg, int nE) {
    int i = blockIdx.x * blockDim.x + threadIdx.x;
    if (i < nE) atomicAdd(&deg[dst[i]], 1);
}

// ---------------------------------------------------------------------------
// Hierarchical exclusive scan of deg -> rowstart; also emits dinv = rsqrt(deg+1)
__global__ void scan1_kernel(const int* __restrict__ deg, int* __restrict__ rowstart,
                             int* __restrict__ bsum, float* __restrict__ dinv, int n) {
    __shared__ int s[256];
    int i = blockIdx.x * 256 + threadIdx.x;
    int v = (i < n) ? deg[i] : 0;
    if (i < n) dinv[i] = rsqrtf((float)v + 1.0f);
    s[threadIdx.x] = v;
    __syncthreads();
    for (int d = 1; d < 256; d <<= 1) {
        int t = (threadIdx.x >= d) ? s[threadIdx.x - d] : 0;
        __syncthreads();
        s[threadIdx.x] += t;
        __syncthreads();
    }
    if (i < n) rowstart[i] = s[threadIdx.x] - v;   // block-local exclusive
    if (threadIdx.x == 255) bsum[blockIdx.x] = s[255];
}

__global__ void scan2_kernel(int* __restrict__ bsum, int* __restrict__ boff, int nb) {
    __shared__ int s[256];
    int t = threadIdx.x;
    int v = (t < nb) ? bsum[t] : 0;
    s[t] = v;
    __syncthreads();
    for (int d = 1; d < 256; d <<= 1) {
        int x = (t >= d) ? s[t - d] : 0;
        __syncthreads();
        s[t] += x;
        __syncthreads();
    }
    if (t < nb) boff[t] = s[t] - v;                 // exclusive block offsets
    if (t == nb - 1) boff[nb] = s[t];               // grand total
}

__global__ void scan3_kernel(int* __restrict__ rowstart, int* __restrict__ cursor,
                             const int* __restrict__ boff, int n, int nb) {
    int i = blockIdx.x * 256 + threadIdx.x;
    if (i < n) {
        int v = rowstart[i] + boff[blockIdx.x];
        rowstart[i] = v;
        cursor[i] = v;
    }
    if (i == n - 1) rowstart[n] = boff[nb];
}

// ---------------------------------------------------------------------------
// CSR scatter: esrc sorted by dst (edinv dropped; agg gathers dinv directly)
__global__ void scatter_kernel(const int* __restrict__ src, const int* __restrict__ dst,
                               int* __restrict__ cursor, int* __restrict__ esrc, int nE) {
    int i = blockIdx.x * blockDim.x + threadIdx.x;
    if (i >= nE) return;
    int s = src[i];
    int d = dst[i];
    int p = atomicAdd(&cursor[d], 1);
    esrc[p] = s;
}

// ---------------------------------------------------------------------------
// W12 = W1 @ W2 (96x96 @ 96x64), bw = b1 @ W2
__global__ void wfuse_kernel(const float* __restrict__ W1, const float* __restrict__ W2,
                             const float* __restrict__ b1, float* __restrict__ W12,
                             float* __restrict__ bw) {
    int idx = blockIdx.x * blockDim.x + threadIdx.x;
    if (idx < 96 * 64) {
        int k = idx >> 6, nn = idx & 63;
        float s = 0.0f;
#pragma unroll
        for (int j = 0; j < 96; ++j) s = fmaf(W1[k * 96 + j], W2[j * 64 + nn], s);
        W12[idx] = s;
    } else if (idx < 96 * 64 + 64) {
        int nn = idx - 96 * 64;
        float s = 0.0f;
#pragma unroll
        for (int j = 0; j < 96; ++j) s = fmaf(b1[j], W2[j * 64 + nn], s);
        bw[nn] = s;
    }
}

// ---------------------------------------------------------------------------
// y[M,64] = A[M,96] @ W[96,64]. 32 rows/block, 8 rows per thread.
__global__ void gemm_kernel(const float* __restrict__ A, const float* __restrict__ W,
                            float* __restrict__ out, int M) {
    __shared__ float sW[96 * 64];
    {
        float4* sW4 = (float4*)sW;
        const float4* W4 = (const float4*)W;
        for (int i = threadIdx.x; i < 96 * 16; i += blockDim.x) sW4[i] = W4[i];
    }
    __syncthreads();

    int col = threadIdx.x & 63;
    int wav = threadIdx.x >> 6;                       // 0..3
    int row0 = __builtin_amdgcn_readfirstlane(blockIdx.x * 32 + wav * 8);
    if (row0 >= M) return;
    const float* a0 = A + (long)row0 * 96;
    float acc[8] = {0, 0, 0, 0, 0, 0, 0, 0};

    if (row0 + 8 <= M) {
#pragma unroll 4
        for (int k = 0; k < 96; k += 4) {
            float w0 = sW[(k + 0) * 64 + col];
            float w1 = sW[(k + 1) * 64 + col];
            float w2 = sW[(k + 2) * 64 + col];
            float w3 = sW[(k + 3) * 64 + col];
#pragma unroll
            for (int r = 0; r < 8; ++r) {
                float4 a = *(const float4*)(a0 + r * 96 + k);
                acc[r] = fmaf(a.x, w0, acc[r]);
                acc[r] = fmaf(a.y, w1, acc[r]);
                acc[r] = fmaf(a.z, w2, acc[r]);
                acc[r] = fmaf(a.w, w3, acc[r]);
            }
        }
#pragma unroll
        for (int r = 0; r < 8; ++r) out[(long)(row0 + r) * 64 + col] = acc[r];
    } else {
        int nr = M - row0;
        for (int k = 0; k < 96; k += 4) {
            float w0 = sW[(k + 0) * 64 + col];
            float w1 = sW[(k + 1) * 64 + col];
            float w2 = sW[(k + 2) * 64 + col];
            float w3 = sW[(k + 3) * 64 + col];
            for (int r = 0; r < nr; ++r) {
                float4 a = *(const float4*)(a0 + r * 96 + k);
                acc[r] = fmaf(a.x, w0, acc[r]);
                acc[r] = fmaf(a.y, w1, acc[r]);
                acc[r] = fmaf(a.z, w2, acc[r]);
                acc[r] = fmaf(a.w, w3, acc[r]);
            }
        }
        for (int r = 0; r < nr; ++r) out[(long)(row0 + r) * 64 + col] = acc[r];
    }
}

// ---------------------------------------------------------------------------
// One 64-lane wave per node:
//   out[i,:] = di^2*y[i,:] + di * sum_e dinv[src_e]*y[src_e,:]   (+ FINAL bias)
// 4-deep unroll, 4 independent accumulators -> 4 gathers in flight.
template <bool FINAL>
__global__ void agg_kernel(const float* __restrict__ y, const int* __restrict__ rowstart,
                           const int* __restrict__ esrc, const float* __restrict__ dinv,
                           const float* __restrict__ bw, const float* __restrict__ b2,
                           float* __restrict__ out, int n) {
    int wid = (blockIdx.x * blockDim.x + threadIdx.x) >> 6;
    int lane = threadIdx.x & 63;
    if (wid >= n) return;
    int rs = rowstart[wid];
    int re = rowstart[wid + 1];
    float di = dinv[wid];
    float self = y[(long)wid * 64 + lane];
    float a0 = 0.0f, a1 = 0.0f, a2 = 0.0f, a3 = 0.0f;
    float sd = 0.0f;
    for (int base = rs; base < re; base += 64) {
        int idx = base + lane;
        bool ok = idx < re;
        int sj = ok ? esrc[idx] : 0;
        float dj = ok ? dinv[sj] : 0.0f;
        sd += dj;
        int nn = min(64, re - base);
        int j = 0;
        for (; j + 4 <= nn; j += 4) {
            int s0 = __shfl(sj, j + 0); float c0 = __shfl(dj, j + 0);
            int s1 = __shfl(sj, j + 1); float c1 = __shfl(dj, j + 1);
            int s2 = __shfl(sj, j + 2); float c2 = __shfl(dj, j + 2);
            int s3 = __shfl(sj, j + 3); float c3 = __shfl(dj, j + 3);
            float v0 = y[(long)s0 * 64 + lane];
            float v1 = y[(long)s1 * 64 + lane];
            float v2 = y[(long)s2 * 64 + lane];
            float v3 = y[(long)s3 * 64 + lane];
            a0 = fmaf(v0, c0, a0);
            a1 = fmaf(v1, c1, a1);
            a2 = fmaf(v2, c2, a2);
            a3 = fmaf(v3, c3, a3);
        }
        for (; j < nn; ++j) {
            int s0 = __shfl(sj, j); float c0 = __shfl(dj, j);
            a0 = fmaf(y[(long)s0 * 64 + lane], c0, a0);
        }
    }
    float acc = fmaf((a0 + a1) + (a2 + a3), di, self * di * di);
    if (FINAL) {
#pragma unroll
        for (int m = 1; m < 64; m <<= 1) sd += __shfl_xor(sd, m);
        float si = di * (di + sd);
        acc = fmaf(si, bw[lane], acc) + b2[lane];
    }
    out[(long)wid * 64 + lane] = acc;
}

// ---------------------------------------------------------------------------
extern "C" void kernel_launch(void* const* d_in, const int* in_sizes, int n_in,
                              void* d_out, int out_size, void* d_ws, size_t ws_size,
                              hipStream_t stream) {
    const float* x  = (const float*)d_in[0];
    const int*   ei = (const int*)d_in[1];
    const float* W1 = (const float*)d_in[2];
    const float* b1 = (const float*)d_in[3];
    const float* W2 = (const float*)d_in[4];
    const float* b2 = (const float*)d_in[5];
    float* out = (float*)d_out;

    const int* src = ei;
    const int* dst = ei + N_EDGES;

    // workspace layout (bytes)
    char* ws = (char*)d_ws;
    float* dinv     = (float*)(ws + 0);                  // 204800
    int*   deg      = (int*)  (ws + 204800);             // 204800
    int*   rowstart = (int*)  (ws + 409600);             // 204800 (n+1 ints)
    int*   cursor   = (int*)  (ws + 614400);             // 204800
    int*   boff     = (int*)  (ws + 819200);             // 1024   (nb+1 ints)
    int*   bsum     = (int*)  (ws + 820224);             // 1024
    float* W12      = (float*)(ws + 821248);             // 24576
    float* bw       = (float*)(ws + 845824);             // 512
    int*   esrc     = (int*)  (ws + 846336);             // 3200000
    float* y        = (float*)(ws + 4046336);            // 12800000
    float* z        = (float*)(ws + 16846336);           // 12800000  (end ~29.6MB)

    // 1) degree (+ dinv inside scan1)
    hipMemsetAsync(deg, 0, N_NODES * sizeof(int), stream);
    deg_kernel<<<(N_EDGES + 255) / 256, 256, 0, stream>>>(dst, deg, N_EDGES);

    // 2) CSR build
    scan1_kernel<<<NB_SCAN, 256, 0, stream>>>(deg, rowstart, bsum, dinv, N_NODES);
    scan2_kernel<<<1, 256, 0, stream>>>(bsum, boff, NB_SCAN);
    scan3_kernel<<<NB_SCAN, 256, 0, stream>>>(rowstart, cursor, boff, N_NODES, NB_SCAN);
    scatter_kernel<<<(N_EDGES + 255) / 256, 256, 0, stream>>>(src, dst, cursor, esrc, N_EDGES);

    // 3) fused weights + single GEMM
    wfuse_kernel<<<(96 * 64 + 64 + 255) / 256, 256, 0, stream>>>(W1, W2, b1, W12, bw);
    gemm_kernel<<<(N_NODES + 31) / 32, 256, 0, stream>>>(x, W12, y, N_NODES);

    // 4) two aggregation passes: z = N y ; out = N z + s*bw + b2
    int aggBlocks = (N_NODES + 3) / 4;  // one 64-lane wave per node, 4 waves/block
    agg_kernel<false><<<aggBlocks, 256, 0, stream>>>(y, rowstart, esrc, dinv, bw, b2, z, N_NODES);
    agg_kernel<true><<<aggBlocks, 256, 0, stream>>>(z, rowstart, esrc, dinv, bw, b2, out, N_NODES);
}

// Round 5
// 138.160 us; speedup vs baseline: 4.9570x; 1.4590x over previous
//
#include <hip/hip_runtime.h>

#define N_NODES 50000
#define N_EDGES 800000
#define NBLKA 200                 // Phase-A blocks; 800000/200 = 4000 edges each
#define EPB (N_EDGES / NBLKA)     // 4000
#define NBUCK 196                 // ceil(50000/256) buckets of 256 nodes
#define MSCAN (256 * NBLKA)       // 51200 hist entries to scan

// ---------------------------------------------------------------------------
// Phase A1: per-block 256-bin histogram of dst>>8, bin-major global layout
__global__ void histA_kernel(const int* __restrict__ dst, int* __restrict__ hist) {
    __shared__ int h[256];
    h[threadIdx.x] = 0;
    __syncthreads();
    int base = blockIdx.x * EPB;
    for (int i = base + threadIdx.x; i < base + EPB; i += 256)
        atomicAdd(&h[dst[i] >> 8], 1);
    __syncthreads();
    hist[threadIdx.x * NBLKA + blockIdx.x] = h[threadIdx.x];
}

// ---------------------------------------------------------------------------
// Hierarchical exclusive scan (generic): in -> out (block-local), bsum per block
__global__ void scan1_kernel(const int* __restrict__ in, int* __restrict__ out,
                             int* __restrict__ bsum, int n) {
    __shared__ int s[256];
    int i = blockIdx.x * 256 + threadIdx.x;
    int v = (i < n) ? in[i] : 0;
    s[threadIdx.x] = v;
    __syncthreads();
    for (int d = 1; d < 256; d <<= 1) {
        int t = (threadIdx.x >= d) ? s[threadIdx.x - d] : 0;
        __syncthreads();
        s[threadIdx.x] += t;
        __syncthreads();
    }
    if (i < n) out[i] = s[threadIdx.x] - v;
    if (threadIdx.x == 255) bsum[blockIdx.x] = s[255];
}

__global__ void scan2_kernel(int* __restrict__ bsum, int* __restrict__ boff, int nb) {
    __shared__ int s[256];
    int t = threadIdx.x;
    int v = (t < nb) ? bsum[t] : 0;
    s[t] = v;
    __syncthreads();
    for (int d = 1; d < 256; d <<= 1) {
        int x = (t >= d) ? s[t - d] : 0;
        __syncthreads();
        s[t] += x;
        __syncthreads();
    }
    if (t < nb) boff[t] = s[t] - v;
    if (t == nb - 1) boff[nb] = s[t];
}

__global__ void scan3_kernel(int* __restrict__ out, const int* __restrict__ boff,
                             int n, int nb) {
    int i = blockIdx.x * 256 + threadIdx.x;
    if (i < n) out[i] += boff[blockIdx.x];
    if (i == n - 1) out[n] = boff[nb];
}

// ---------------------------------------------------------------------------
// Phase A2: scatter (src,dst) pairs to bucket-major ebuf using per-(block,bin)
// offsets from the scanned histogram. Runs are contiguous -> ~full-line writes.
__global__ void scatterA_kernel(const int* __restrict__ src, const int* __restrict__ dst,
                                const int* __restrict__ scanned, int2* __restrict__ ebuf) {
    __shared__ int off[256];
    off[threadIdx.x] = scanned[threadIdx.x * NBLKA + blockIdx.x];
    __syncthreads();
    int base = blockIdx.x * EPB;
    for (int i = base + threadIdx.x; i < base + EPB; i += 256) {
        int s = src[i];
        int d = dst[i];
        int p = atomicAdd(&off[d >> 8], 1);
        ebuf[p] = make_int2(s, d);
    }
}

// ---------------------------------------------------------------------------
// Phase B: one block per 256-node bucket. Counts per-node degree in LDS,
// LDS-scan -> rowstart + dinv, then LDS-cursor scatter of esrc (no global
// atomics; each bucket's esrc region is written by exactly one block).
__global__ void bucket_kernel(const int2* __restrict__ ebuf, const int* __restrict__ scanned,
                              int* __restrict__ rowstart, float* __restrict__ dinv,
                              int* __restrict__ esrc) {
    __shared__ int cnt[256];
    __shared__ int cur[256];
    __shared__ int s[256];
    int k = blockIdx.x;
    int tid = threadIdx.x;
    int base = scanned[k * NBLKA];
    int end  = scanned[(k + 1) * NBLKA];
    cnt[tid] = 0;
    __syncthreads();
    for (int i = base + tid; i < end; i += 256)
        atomicAdd(&cnt[ebuf[i].y & 255], 1);
    __syncthreads();
    int v = cnt[tid];
    s[tid] = v;
    __syncthreads();
    for (int d = 1; d < 256; d <<= 1) {
        int t = (tid >= d) ? s[tid - d] : 0;
        __syncthreads();
        s[tid] += t;
        __syncthreads();
    }
    int excl = s[tid] - v;
    int node = (k << 8) + tid;
    cur[tid] = base + excl;
    if (node < N_NODES) {
        rowstart[node] = base + excl;
        dinv[node] = rsqrtf((float)v + 1.0f);
    }
    if (k == 0 && tid == 0) rowstart[N_NODES] = N_EDGES;
    __syncthreads();
    for (int i = base + tid; i < end; i += 256) {
        int2 e = ebuf[i];
        int p = atomicAdd(&cur[e.y & 255], 1);
        esrc[p] = e.x;
    }
}

// ---------------------------------------------------------------------------
// W12 = W1 @ W2 (96x96 @ 96x64), bw = b1 @ W2
__global__ void wfuse_kernel(const float* __restrict__ W1, const float* __restrict__ W2,
                             const float* __restrict__ b1, float* __restrict__ W12,
                             float* __restrict__ bw) {
    int idx = blockIdx.x * blockDim.x + threadIdx.x;
    if (idx < 96 * 64) {
        int k = idx >> 6, nn = idx & 63;
        float s = 0.0f;
#pragma unroll
        for (int j = 0; j < 96; ++j) s = fmaf(W1[k * 96 + j], W2[j * 64 + nn], s);
        W12[idx] = s;
    } else if (idx < 96 * 64 + 64) {
        int nn = idx - 96 * 64;
        float s = 0.0f;
#pragma unroll
        for (int j = 0; j < 96; ++j) s = fmaf(b1[j], W2[j * 64 + nn], s);
        bw[nn] = s;
    }
}

// ---------------------------------------------------------------------------
// y[M,64] = A[M,96] @ W[96,64]. 32 rows/block, 8 rows per thread.
__global__ void gemm_kernel(const float* __restrict__ A, const float* __restrict__ W,
                            float* __restrict__ out, int M) {
    __shared__ float sW[96 * 64];
    {
        float4* sW4 = (float4*)sW;
        const float4* W4 = (const float4*)W;
        for (int i = threadIdx.x; i < 96 * 16; i += blockDim.x) sW4[i] = W4[i];
    }
    __syncthreads();

    int col = threadIdx.x & 63;
    int wav = threadIdx.x >> 6;
    int row0 = __builtin_amdgcn_readfirstlane(blockIdx.x * 32 + wav * 8);
    if (row0 >= M) return;
    const float* a0 = A + (long)row0 * 96;
    float acc[8] = {0, 0, 0, 0, 0, 0, 0, 0};

    if (row0 + 8 <= M) {
#pragma unroll 4
        for (int k = 0; k < 96; k += 4) {
            float w0 = sW[(k + 0) * 64 + col];
            float w1 = sW[(k + 1) * 64 + col];
            float w2 = sW[(k + 2) * 64 + col];
            float w3 = sW[(k + 3) * 64 + col];
#pragma unroll
            for (int r = 0; r < 8; ++r) {
                float4 a = *(const float4*)(a0 + r * 96 + k);
                acc[r] = fmaf(a.x, w0, acc[r]);
                acc[r] = fmaf(a.y, w1, acc[r]);
                acc[r] = fmaf(a.z, w2, acc[r]);
                acc[r] = fmaf(a.w, w3, acc[r]);
            }
        }
#pragma unroll
        for (int r = 0; r < 8; ++r) out[(long)(row0 + r) * 64 + col] = acc[r];
    } else {
        int nr = M - row0;
        for (int k = 0; k < 96; k += 4) {
            float w0 = sW[(k + 0) * 64 + col];
            float w1 = sW[(k + 1) * 64 + col];
            float w2 = sW[(k + 2) * 64 + col];
            float w3 = sW[(k + 3) * 64 + col];
            for (int r = 0; r < nr; ++r) {
                float4 a = *(const float4*)(a0 + r * 96 + k);
                acc[r] = fmaf(a.x, w0, acc[r]);
                acc[r] = fmaf(a.y, w1, acc[r]);
                acc[r] = fmaf(a.z, w2, acc[r]);
                acc[r] = fmaf(a.w, w3, acc[r]);
            }
        }
        for (int r = 0; r < nr; ++r) out[(long)(row0 + r) * 64 + col] = acc[r];
    }
}

// ---------------------------------------------------------------------------
// One 64-lane wave per node:
//   out[i,:] = di^2*y[i,:] + di * sum_e dinv[src_e]*y[src_e,:]   (+ FINAL bias)
template <bool FINAL>
__global__ void agg_kernel(const float* __restrict__ y, const int* __restrict__ rowstart,
                           const int* __restrict__ esrc, const float* __restrict__ dinv,
                           const float* __restrict__ bw, const float* __restrict__ b2,
                           float* __restrict__ out, int n) {
    int wid = (blockIdx.x * blockDim.x + threadIdx.x) >> 6;
    int lane = threadIdx.x & 63;
    if (wid >= n) return;
    int rs = rowstart[wid];
    int re = rowstart[wid + 1];
    float di = dinv[wid];
    float self = y[(long)wid * 64 + lane];
    float a0 = 0.0f, a1 = 0.0f, a2 = 0.0f, a3 = 0.0f;
    float sd = 0.0f;
    for (int base = rs; base < re; base += 64) {
        int idx = base + lane;
        bool ok = idx < re;
        int sj = ok ? esrc[idx] : 0;
        float dj = ok ? dinv[sj] : 0.0f;
        sd += dj;
        int nn = min(64, re - base);
        int j = 0;
        for (; j + 4 <= nn; j += 4) {
            int s0 = __shfl(sj, j + 0); float c0 = __shfl(dj, j + 0);
            int s1 = __shfl(sj, j + 1); float c1 = __shfl(dj, j + 1);
            int s2 = __shfl(sj, j + 2); float c2 = __shfl(dj, j + 2);
            int s3 = __shfl(sj, j + 3); float c3 = __shfl(dj, j + 3);
            float v0 = y[(long)s0 * 64 + lane];
            float v1 = y[(long)s1 * 64 + lane];
            float v2 = y[(long)s2 * 64 + lane];
            float v3 = y[(long)s3 * 64 + lane];
            a0 = fmaf(v0, c0, a0);
            a1 = fmaf(v1, c1, a1);
            a2 = fmaf(v2, c2, a2);
            a3 = fmaf(v3, c3, a3);
        }
        for (; j < nn; ++j) {
            int s0 = __shfl(sj, j); float c0 = __shfl(dj, j);
            a0 = fmaf(y[(long)s0 * 64 + lane], c0, a0);
        }
    }
    float acc = fmaf((a0 + a1) + (a2 + a3), di, self * di * di);
    if (FINAL) {
#pragma unroll
        for (int m = 1; m < 64; m <<= 1) sd += __shfl_xor(sd, m);
        float si = di * (di + sd);
        acc = fmaf(si, bw[lane], acc) + b2[lane];
    }
    out[(long)wid * 64 + lane] = acc;
}

// ---------------------------------------------------------------------------
extern "C" void kernel_launch(void* const* d_in, const int* in_sizes, int n_in,
                              void* d_out, int out_size, void* d_ws, size_t ws_size,
                              hipStream_t stream) {
    const float* x  = (const float*)d_in[0];
    const int*   ei = (const int*)d_in[1];
    const float* W1 = (const float*)d_in[2];
    const float* b1 = (const float*)d_in[3];
    const float* W2 = (const float*)d_in[4];
    const float* b2 = (const float*)d_in[5];
    float* out = (float*)d_out;

    const int* src = ei;
    const int* dst = ei + N_EDGES;

    // workspace layout (bytes); ebuf aliases z (disjoint lifetimes)
    char* ws = (char*)d_ws;
    float* dinv     = (float*)(ws + 0);                  // 204800
    int*   rowstart = (int*)  (ws + 204800);             // 200004 -> pad 204800
    int*   hist     = (int*)  (ws + 409600);             // 204800 (51200 ints)
    int*   scanned  = (int*)  (ws + 614400);             // 204804 -> pad 208896
    int*   bsum     = (int*)  (ws + 823296);             // 1024
    int*   boff     = (int*)  (ws + 824320);             // 1024
    float* W12      = (float*)(ws + 825344);             // 24576
    float* bw       = (float*)(ws + 849920);             // 512
    int*   esrc     = (int*)  (ws + 850432);             // 3200000
    float* y        = (float*)(ws + 4050432);            // 12800000
    int2*  ebuf     = (int2*) (ws + 16850432);           // 6400000 (aliases z)
    float* z        = (float*)(ws + 16850432);           // 12800000 (end 29.65MB)

    // Phase A: bucket edges by dst>>8 with full-line writes
    histA_kernel<<<NBLKA, 256, 0, stream>>>(dst, hist);
    scan1_kernel<<<MSCAN / 256, 256, 0, stream>>>(hist, scanned, bsum, MSCAN);
    scan2_kernel<<<1, 256, 0, stream>>>(bsum, boff, MSCAN / 256);
    scan3_kernel<<<MSCAN / 256, 256, 0, stream>>>(scanned, boff, MSCAN, MSCAN / 256);
    scatterA_kernel<<<NBLKA, 256, 0, stream>>>(src, dst, scanned, ebuf);

    // Phase B: per-bucket degree count + rowstart + dinv + LDS-cursor scatter
    bucket_kernel<<<NBUCK, 256, 0, stream>>>(ebuf, scanned, rowstart, dinv, esrc);

    // fused weights + single GEMM
    wfuse_kernel<<<(96 * 64 + 64 + 255) / 256, 256, 0, stream>>>(W1, W2, b1, W12, bw);
    gemm_kernel<<<(N_NODES + 31) / 32, 256, 0, stream>>>(x, W12, y, N_NODES);

    // two aggregation passes: z = N y ; out = N z + s*bw + b2
    int aggBlocks = (N_NODES + 3) / 4;  // one 64-lane wave per node, 4 waves/block
    agg_kernel<false><<<aggBlocks, 256, 0, stream>>>(y, rowstart, esrc, dinv, bw, b2, z, N_NODES);
    agg_kernel<true><<<aggBlocks, 256, 0, stream>>>(z, rowstart, esrc, dinv, bw, b2, out, N_NODES);
}